// Round 8
// baseline (3353.519 us; speedup 1.0000x reference)
//
#include <hip/hip_runtime.h>
#include <math.h>
#include <stdint.h>

// VanillaRNN, bit-exact (R9-lineage). Numerics FROZEN:
//   * z[i] = ascending-k single FMA chain k=0..255, init 0, split P: k=0..127
//     -> exact float LDS handoff (zpart) -> Q: k=128..255.
//   * z = ((W_hx*x_t) + chain) + bias_h, separately rounded, left-assoc
//   * tanh = Eigen/XLA fast-tanh WITH FMA (clamp 7.99881172180175781f)
//
// R17 — kill the AGPR-copy tax via per-use "v" constraints.
//   Evidence: VALUBusy*wall is ~2300 cyc/SIMD/u-iter in R9/R15/R16 — even
//   R15 with ZERO LDS reads. Pure FMA issue = 1024. The constant +1100 =
//   128 v_accvgpr_read/body: w parked in AGPRs every round (VGPR_Count
//   76-88 with 128 live w). Soft hints failed (R10 waves_per_eu -> 88;
//   R11 forcing -> spill). Arch demand ~160 <= 256 budget at 2 waves/SIMD
//   — it fits; the RA just AGPR-parks kernel-long live ranges.
//   Fix: chain FMAs as inline-asm v_fma_f32 with hard "v" constraint on w
//   at EVERY use — AGPR residence now costs a copy per use, so the RA
//   keeps w in arch VGPRs. v_fma_f32 == fmaf, z-chain order enforced by
//   "+v"(z) dataflow => bit-exact. SMEM-half h consumed via "s" operand
//   (1 SGPR read per VALU op, legal) — no s->v copies either.
//   Split rebalanced 48/80 -> 64/64: 64 LDS-FMAs (~256 cyc dep-paced)
//   cover the L2 round trip of the 8 s_load_dwordx8; WAIT carries "+v"(z)
//   so it cannot float above the LDS half (keeps latency covered).
// Skeleton = R9/R16 verbatim: literal-offset x2-unrolled STEP, same
// staging, same barriers, same epilogue.
// Schedule (audited): phaseA(u): P(col0,u,rp) | Q(col1,u-1,rp^1) [u>=1];
// phaseB(u): P(col1,u,rp) | Q(col0,u,rp); drain Q(col1,TT-1,0); rp=(u&1)^1.
// Workspace: 256 WGs x 2 cols x 2 parities x 256 floats = 1 MB of d_ws.

#define TT 2048
#define BB 512
#define HH 256
#define CC 10
#define KH 128   // chain half-length per thread group

typedef __attribute__((ext_vector_type(8))) int i8x;

__device__ __forceinline__ float ref_tanhf(float x)
{
    const float a1  = 4.89352455891786e-03f;
    const float a3  = 6.37261928875436e-04f;
    const float a5  = 1.48572235717979e-05f;
    const float a7  = 5.12229709037114e-08f;
    const float a9  = -8.60467152213735e-11f;
    const float a11 = 2.00018790482477e-13f;
    const float a13 = -2.76076847742355e-16f;
    const float b0  = 4.89352518554385e-03f;
    const float b2  = 2.26843463243900e-03f;
    const float b4  = 1.18534705686654e-04f;
    const float b6  = 1.19825839466702e-06f;

    const float kClamp = 7.99881172180175781f;
    const float xc = fmaxf(fminf(x, kClamp), -kClamp);
    const float x2 = __fmul_rn(xc, xc);
    float p = fmaf(x2, a13, a11);
    p = fmaf(x2, p, a9);
    p = fmaf(x2, p, a7);
    p = fmaf(x2, p, a5);
    p = fmaf(x2, p, a3);
    p = fmaf(x2, p, a1);
    p = __fmul_rn(xc, p);
    float q = fmaf(x2, b6, b4);
    q = fmaf(x2, q, b2);
    q = fmaf(x2, q, b0);
    const float r = __fdiv_rn(p, q);
    return (fabsf(x) < 0.0004f) ? x : r;
}

__global__ __launch_bounds__(512, 2)
void rnn_fwd(const float* __restrict__ x,
             const float* __restrict__ W_hx,
             const float* __restrict__ W_hh,
             const float* __restrict__ W_ph,
             const float* __restrict__ bias_h,
             const float* __restrict__ bias_p,
             float* __restrict__ out,
             float* __restrict__ ws)
{
    const int tid   = threadIdx.x;
    const int group = tid >> 8;        // 0 = P (k 0..127), 1 = Q (k 128..255)
    const int i     = tid & (HH - 1);  // hidden row
    const int b0    = blockIdx.x * 2;  // two batch columns per WG

    __shared__ __align__(16) float xls[2][TT];        // 16 KB
    __shared__ __align__(16) float hbuf[2][2][HH];    // [col][parity][row] 4 KB
    __shared__ __align__(16) float zpart[2][HH];      // 2 KB

    // per-WG h region in global: [col][parity][row], 4 KB (SMEM half source)
    float* __restrict__ hg = ws + (size_t)blockIdx.x * (2 * 2 * HH);

    // --- stage: this thread's half-row of W_hh -> 128 regs ---
    float w[KH];
    const float* __restrict__ wrow = W_hh + (size_t)i * HH + group * KH;
#pragma unroll
    for (int k = 0; k < KH; k += 4) {
        const float4 v = *reinterpret_cast<const float4*>(wrow + k);
        w[k] = v.x; w[k + 1] = v.y; w[k + 2] = v.z; w[k + 3] = v.w;
    }
#pragma unroll
    for (int k = 0; k < KH; ++k) {
        asm volatile("" : "+v"(w[k]));   // block rematerialization
    }

    // --- stage: x rows (2*TT contiguous floats) -> LDS, 512 threads ---
    {
        const float4* __restrict__ xsrc =
            reinterpret_cast<const float4*>(x + (size_t)b0 * TT);
        float4* __restrict__ xdst = reinterpret_cast<float4*>(&xls[0][0]);
        xdst[tid]       = xsrc[tid];
        xdst[512 + tid] = xsrc[512 + tid];
    }
    const float whx = W_hx[i];     // used by Q only
    const float bh  = bias_h[i];   // used by Q only

    // h(-1)=0 at parity 1 in BOTH stores (step t reads (t&1)^1, writes t&1)
    hbuf[group][1][i] = 0.0f;                // col=group, par=1, row=i
    hg[(group * 2 + 1) * HH + i] = 0.0f;
    __syncthreads();                         // drains lgkm + vmcnt(0)

// K$ invalidate: SMEM half reads hg written last phase (same WG, via L2).
#define KINV asm volatile("s_dcache_inv\n\ts_waitcnt lgkmcnt(0)" ::: "memory")

// one s_load_dwordx8 at literal byte offset IMM from wave-uniform base hb
#define SL(DST, IMM)                                                          \
    asm volatile("s_load_dwordx8 %0, %1, " IMM                                \
                 : "=s"(DST) : "s"(hb) : "memory")

// wait; pass-through defs on octs AND z: cannot float above the LDS-half
// FMA chain (z dep) nor let SMEM FMAs hoist above it (oct dep). rule-18 safe.
#define WAIT8Z(A, B, C, D, E, F, G, H)                                        \
    asm volatile("s_waitcnt lgkmcnt(0)"                                       \
                 : "+s"(A), "+s"(B), "+s"(C), "+s"(D),                        \
                   "+s"(E), "+s"(F), "+s"(G), "+s"(H), "+v"(z))

// chain FMA, w hard-constrained to arch VGPR ("v"); h from VGPR or SGPR.
// v_fma_f32 == fmaf (single rounding); z dataflow enforces ascending order.
#define VFMAV(W, H)                                                           \
    asm("v_fma_f32 %0, %1, %2, %0" : "+v"(z) : "v"(W), "v"(H));
#define VFMAS(W, H)                                                           \
    asm("v_fma_f32 %0, %1, %2, %0" : "+v"(z) : "v"(W), "s"(H));

// 4 chain FMAs from one broadcast ds_read_b128 at literal offset HB+KL.
#define BCA4(KL, HB)                                                          \
    {                                                                         \
        const float4 h4 = *reinterpret_cast<const float4*>(h + (HB) + (KL));  \
        VFMAV(w[(KL) + 0], h4.x)                                              \
        VFMAV(w[(KL) + 1], h4.y)                                              \
        VFMAV(w[(KL) + 2], h4.z)                                              \
        VFMAV(w[(KL) + 3], h4.w)                                              \
    }
#define BC64(HB)                                                              \
    BCA4(0, HB)  BCA4(4, HB)  BCA4(8, HB)  BCA4(12, HB)                       \
    BCA4(16, HB) BCA4(20, HB) BCA4(24, HB) BCA4(28, HB)                       \
    BCA4(32, HB) BCA4(36, HB) BCA4(40, HB) BCA4(44, HB)                       \
    BCA4(48, HB) BCA4(52, HB) BCA4(56, HB) BCA4(60, HB)

// 8 chain FMAs; h element is a wave-uniform SGPR operand (ascending k).
#define SFMA8(MT, K)                                                          \
    VFMAS(w[(K) + 0], MT[0]) VFMAS(w[(K) + 1], MT[1])                         \
    VFMAS(w[(K) + 2], MT[2]) VFMAS(w[(K) + 3], MT[3])                         \
    VFMAS(w[(K) + 4], MT[4]) VFMAS(w[(K) + 5], MT[5])                         \
    VFMAS(w[(K) + 6], MT[6]) VFMAS(w[(K) + 7], MT[7])

#define SFMA64                                                                \
    SFMA8(m0, 64) SFMA8(m1, 72) SFMA8(m2, 80)  SFMA8(m3, 88)                  \
    SFMA8(m4, 96) SFMA8(m5, 104) SFMA8(m6, 112) SFMA8(m7, 120)

// P half-chain: k = 0..63 via LDS, k = 64..127 via SMEM (bytes 0x100-0x1FF).
#define PBODY(COL, T, RP)                                                     \
    {                                                                         \
        KINV;                                                                 \
        const uint64_t hb =                                                   \
            (uint64_t)(uintptr_t)(hg + ((COL) * 2 + (RP)) * HH);              \
        i8x m0, m1, m2, m3, m4, m5, m6, m7;                                   \
        SL(m0, "0x100"); SL(m1, "0x120"); SL(m2, "0x140"); SL(m3, "0x160");   \
        SL(m4, "0x180"); SL(m5, "0x1A0"); SL(m6, "0x1C0"); SL(m7, "0x1E0");   \
        const float* __restrict__ h = &hbuf[(COL)][(RP)][0];                  \
        float z = 0.0f;                                                       \
        BC64(0)                                                               \
        WAIT8Z(m0, m1, m2, m3, m4, m5, m6, m7);                               \
        SFMA64                                                                \
        zpart[(COL)][i] = z;                                                  \
    }

// Q half-chain: k = 128..191 via LDS (hbuf+128), k = 192..255 via SMEM
// (bytes 0x300-0x3FF); then x/bias/tanh, store BOTH hbuf and hg at RP^1.
#define QBODY(COL, T, RP)                                                     \
    {                                                                         \
        KINV;                                                                 \
        const uint64_t hb =                                                   \
            (uint64_t)(uintptr_t)(hg + ((COL) * 2 + (RP)) * HH);              \
        i8x m0, m1, m2, m3, m4, m5, m6, m7;                                   \
        SL(m0, "0x300"); SL(m1, "0x320"); SL(m2, "0x340"); SL(m3, "0x360");   \
        SL(m4, "0x380"); SL(m5, "0x3A0"); SL(m6, "0x3C0"); SL(m7, "0x3E0");   \
        const float* __restrict__ h = &hbuf[(COL)][(RP)][0];                  \
        float z = zpart[(COL)][i];                                            \
        BC64(KH)                                                              \
        WAIT8Z(m0, m1, m2, m3, m4, m5, m6, m7);                               \
        SFMA64                                                                \
        const float a0 = __fmul_rn(whx, xls[(COL)][(T)]);                     \
        z = __fadd_rn(__fadd_rn(a0, z), bh);                                  \
        const float hv = ref_tanhf(z);                                        \
        hbuf[(COL)][(RP) ^ 1][i] = hv;                                        \
        hg[((COL) * 2 + ((RP) ^ 1)) * HH + i] = hv;                           \
    }

// One u-iteration with compile-time read-parity RP = (u&1)^1.
#define STEP(U, RP)                                                           \
    {                                                                         \
        if (group == 0) { PBODY(0, (U), (RP)) }                               \
        else if ((U) >= 1) { QBODY(1, (U) - 1, (RP) ^ 1) }                    \
        __syncthreads();                                                      \
        if (group == 0) { PBODY(1, (U), (RP)) }                               \
        else { QBODY(0, (U), (RP)) }                                          \
        __syncthreads();                                                      \
    }

    // u=0 peeled (resolves the u>=1 guard), then pairs with constant parity.
    STEP(0, 1)
    for (int u = 1; u + 1 < TT; u += 2) {
        STEP(u, 0)
        STEP(u + 1, 1)
    }
    STEP(TT - 1, 0)                       // u = 2047 (odd -> rp = 0)
    if (group == 1) { QBODY(1, TT - 1, 0) }   // drain pipeline: col1, last step
    __syncthreads();

#undef STEP
#undef QBODY
#undef PBODY
#undef SFMA64
#undef SFMA8
#undef BC64
#undef BCA4
#undef VFMAS
#undef VFMAV
#undef WAIT8Z
#undef SL
#undef KINV

    // epilogue: p[b,c] = sum_k h_T[k]*W_ph[c,k] + bias_p[c]
    // last step t = TT-1 wrote parity (TT-1)&1 = 1; full h is in LDS hbuf.
    if (tid < 2 * CC) {
        const int col = tid / CC;
        const int c   = tid % CC;
        const float* __restrict__ wp = W_ph + (size_t)c * HH;
        const float* __restrict__ hf = hbuf[col][1];
        float pv = 0.0f;
#pragma unroll 8
        for (int k = 0; k < HH; ++k) {
            pv = fmaf(hf[k], wp[k], pv);
        }
        out[(size_t)(b0 + col) * CC + c] = __fadd_rn(pv, bias_p[c]);
    }
}

extern "C" void kernel_launch(void* const* d_in, const int* in_sizes, int n_in,
                              void* d_out, int out_size, void* d_ws, size_t ws_size,
                              hipStream_t stream) {
    const float* x      = (const float*)d_in[0];
    const float* W_hx   = (const float*)d_in[1];
    const float* W_hh   = (const float*)d_in[2];
    const float* W_ph   = (const float*)d_in[3];
    const float* bias_h = (const float*)d_in[4];
    const float* bias_p = (const float*)d_in[5];
    float* out = (float*)d_out;
    float* ws  = (float*)d_ws;   // 256 WGs * 1024 floats * 4B = 1 MB

    rnn_fwd<<<dim3(BB / 2), dim3(512), 0, stream>>>(x, W_hx, W_hh, W_ph,
                                                    bias_h, bias_p, out, ws);
}